// Round 15
// baseline (286.730 us; speedup 1.0000x reference)
//
#include <hip/hip_runtime.h>
#include <hip/hip_bf16.h>
#include <stdint.h>

#define SS    2048      // sequence length
#define BB    2         // batch
#define MT    4096      // B*S rows
#define DM    2048      // d_model
#define NQKVC 3072      // fused QKV output cols: 2048 Q + 512 K + 512 V

typedef __attribute__((ext_vector_type(8))) short s16x8;
typedef __attribute__((ext_vector_type(4))) short s16x4;
typedef __attribute__((ext_vector_type(4))) float f32x4;
typedef __attribute__((ext_vector_type(2))) unsigned u32x2;

typedef __attribute__((address_space(1))) const void* as1cv;
typedef __attribute__((address_space(3))) void* as3v;

__device__ __forceinline__ float b2f(int u) {
  union { unsigned u; float f; } x; x.u = ((unsigned)(u & 0xFFFF)) << 16; return x.f;
}
__device__ __forceinline__ short f2b(float f) {
  union { float f; unsigned u; } x; x.f = f;
  unsigned r = x.u + 0x7FFFu + ((x.u >> 16) & 1u);
  return (short)(r >> 16);
}
// async global->LDS, 16B per lane. Dest is wave-uniform base; HW adds lane*16.
__device__ __forceinline__ void gld16(const void* g, void* l) {
  __builtin_amdgcn_global_load_lds((as1cv)(uintptr_t)g, (as3v)(uint32_t)(uintptr_t)l, 16, 0, 0);
}
// swizzled LDS tile read: rows of 128B, byte ^= (row&7)<<4
__device__ __forceinline__ s16x8 ldsfrag(const char* tile, int r, int cb) {
  return *(const s16x8*)(tile + r * 128 + (cb ^ ((r & 7) << 4)));
}
__device__ __forceinline__ f32x4 mfma16(s16x8 a, s16x8 b, f32x4 c) {
  return __builtin_amdgcn_mfma_f32_16x16x32_bf16(a, b, c, 0, 0, 0);
}
// bijective XCD-chunking swizzle (requires gridDim.x*gridDim.y % 8 == 0)
__device__ __forceinline__ void swz8(int& bx, int& by) {
  int gx = gridDim.x;
  int lin = by * gx + bx;
  int tot = gx * gridDim.y;
  int s = (lin & 7) * (tot >> 3) + (lin >> 3);
  bx = s % gx;
  by = s / gx;
}

// ---------------- merged prep: x->bf16, 4 weight transposes, RoPE table ----------------
// blocks [0,8192): xcvt  [8192,12288): Wq  [12288,13312): Wk  [13312,14336): Wv
//        [14336,18432): Wo  [18432,18688): rtab
__global__ __launch_bounds__(256) void k_wpre(const float* __restrict__ x,
                                              const float* __restrict__ Wq,
                                              const float* __restrict__ Wk,
                                              const float* __restrict__ Wv,
                                              const float* __restrict__ Wo,
                                              ushort* __restrict__ xb,
                                              ushort* __restrict__ Wqkvt,
                                              ushort* __restrict__ Wot,
                                              float* __restrict__ rtab) {
  __shared__ float t[32][33];
  int bid = blockIdx.x;
  if (bid < 8192) {
    int i = (bid * 256 + threadIdx.x) * 4;
    float4 v = *(const float4*)(x + i);
    s16x4 o = { f2b(v.x), f2b(v.y), f2b(v.z), f2b(v.w) };
    *(s16x4*)(xb + i) = o;
    return;
  }
  bid -= 8192;
  if (bid >= 10240) {
    int idx = (bid - 10240) * 256 + threadIdx.x;   // s*32 + d
    int d = idx & 31, s = idx >> 5;
    float invf = exp2f(-(float)d * (18.931568569324174f / 32.0f));
    float sn, c;
    sincosf((float)s * invf, &sn, &c);
    rtab[idx * 2]     = c;
    rtab[idx * 2 + 1] = sn;
    return;
  }
  const float* W; ushort* out; int N; int l;
  if (bid < 4096)      { W = Wq; out = Wqkvt;                         N = 2048; l = bid; }
  else if (bid < 5120) { W = Wk; out = Wqkvt + (size_t)2048 * 2048;   N = 512;  l = bid - 4096; }
  else if (bid < 6144) { W = Wv; out = Wqkvt + (size_t)2560 * 2048;   N = 512;  l = bid - 5120; }
  else                 { W = Wo; out = Wot;                           N = 2048; l = bid - 6144; }
  int k0 = (l & 63) * 32, n0 = (l >> 6) * 32;
  int tx = threadIdx.x & 31, ty = threadIdx.x >> 5;
#pragma unroll
  for (int j = 0; j < 32; j += 8)
    t[ty + j][tx] = W[(size_t)(k0 + ty + j) * N + n0 + tx];
  __syncthreads();
  // vectorized transposed store: ushort2 per thread, 2 iterations
  int tx2 = threadIdx.x & 15, rr = threadIdx.x >> 4;   // rr in [0,16)
#pragma unroll
  for (int j = 0; j < 32; j += 16) {
    int nl = rr + j;
    ushort2 w;
    w.x = (ushort)f2b(t[tx2 * 2][nl]);
    w.y = (ushort)f2b(t[tx2 * 2 + 1][nl]);
    *(ushort2*)(out + (size_t)(n0 + nl) * 2048 + k0 + tx2 * 2) = w;
  }
}

// ---------------- GEMM: C[M][N] = A[M][K] * B^T (B is [N][K]), all bf16, fp32 acc ----------------
// 128x128 tile, BK=64, 4 waves (2x2), each wave 64x64 = 4x4 frags of 16x16x32 MFMA.
// ROPE=1: rotary embedding on Q/K bands in the fp32 epilogue via the precomputed table;
// Q band pre-scaled by 0.125*log2(e). V band (col0 >= 2560) writes TRANSPOSED to Vt
// via LDS staging (fuses the old k_vt kernel) and skips the C write.
template <int BF16_OUT, int ROPE>
__global__ __launch_bounds__(256) void k_gemm(const ushort* __restrict__ A,
                                              const ushort* __restrict__ B,
                                              void* __restrict__ Cv,
                                              const float* __restrict__ rtab,
                                              ushort* __restrict__ Vt,
                                              int M, int N, int K) {
  __shared__ __align__(16) char lds[32768];
  char* ldsA = lds;
  char* ldsB = lds + 16384;
  int bx = blockIdx.x, by = blockIdx.y;
  swz8(bx, by);
  int tid = threadIdx.x, lane = tid & 63, wid = tid >> 6;
  int wr = wid >> 1, wc = wid & 1;
  int row0 = by * 128, col0 = bx * 128;
  int fr = lane & 15, fq = lane >> 4;
  f32x4 acc[4][4] = {};
  int rl = lane >> 3;                                   // row within 8-row chunk
  int cbs = ((lane & 7) << 4) ^ (rl << 4);              // pre-swizzled source byte-in-row
  const char* Ab = (const char*)A;
  const char* Bb = (const char*)B;
  size_t ldb = (size_t)K * 2;

  for (int kt = 0; kt < K; kt += 64) {
#pragma unroll
    for (int i = 0; i < 4; i++) {
      int ra = wid * 32 + i * 8 + rl;
      gld16(Ab + (size_t)(row0 + ra) * ldb + (size_t)kt * 2 + cbs,
            ldsA + (wid * 32 + i * 8) * 128);
      gld16(Bb + (size_t)(col0 + ra) * ldb + (size_t)kt * 2 + cbs,
            ldsB + (wid * 32 + i * 8) * 128);
    }
    __syncthreads();
#pragma unroll
    for (int kk = 0; kk < 2; kk++) {
      int cb = kk * 64 + (fq << 4);
      s16x8 af[4], bg[4];
#pragma unroll
      for (int m = 0; m < 4; m++) af[m] = ldsfrag(ldsA, wr * 64 + m * 16 + fr, cb);
#pragma unroll
      for (int n = 0; n < 4; n++) bg[n] = ldsfrag(ldsB, wc * 64 + n * 16 + fr, cb);
#pragma unroll
      for (int m = 0; m < 4; m++)
#pragma unroll
        for (int n = 0; n < 4; n++)
          acc[m][n] = mfma16(af[m], bg[n], acc[m][n]);
    }
    __syncthreads();
  }

  int cb0 = col0 + wc * 64;              // 64-col wave band

  if (ROPE && col0 >= 2560) {
    // ---- V band: transpose to Vt[b*512 + (c-2560)][s] via LDS, skip C write ----
    __syncthreads();                     // all waves done reading ldsA/B
    char* tw = lds + wid * 8192;         // per-wave [64 col][64 s] bf16, swizzled rows of 128B
#pragma unroll
    for (int m = 0; m < 4; m++)
#pragma unroll
      for (int n = 0; n < 4; n++) {
        int cl = n * 16 + fr;
        unsigned u01, u23;
        asm("v_cvt_pk_bf16_f32 %0, %1, %2" : "=v"(u01) : "v"(acc[m][n][0]), "v"(acc[m][n][1]));
        asm("v_cvt_pk_bf16_f32 %0, %1, %2" : "=v"(u23) : "v"(acc[m][n][2]), "v"(acc[m][n][3]));
        u32x2 w = {u01, u23};
        *(u32x2*)(tw + cl * 128 + (((m * 16 + fq * 4) * 2) ^ ((cl & 7) << 4))) = w;
      }
    asm volatile("" ::: "memory");
    int b = row0 >> 11;                  // batch index (blocks never straddle b)
    int s0 = row0 - b * 2048 + wr * 64;  // this wave's 64 s-rows
    int vrow0 = b * 512 + (cb0 - 2560);
#pragma unroll
    for (int jj = 0; jj < 8; jj++) {
      int cl = jj * 8 + (lane >> 3);
      int ch = lane & 7;
      s16x8 v = *(const s16x8*)(tw + cl * 128 + ((ch * 16) ^ ((cl & 7) << 4)));
      *(s16x8*)(Vt + (size_t)(vrow0 + cl) * SS + s0 + ch * 8) = v;
    }
    return;
  }

  if (ROPE) {
    if (cb0 < 2560) {                    // Q band (<2048) or K band (2048..2559)
      float qs = (cb0 < 2048) ? 0.18033688011112042f : 1.0f;
#pragma unroll
      for (int m = 0; m < 4; m++)
#pragma unroll
        for (int i = 0; i < 4; i++) {
          int srow = (row0 + wr * 64 + m * 16 + fq * 4 + i) & (SS - 1);
          const float* tr = rtab + srow * 64;
          float cs0 = tr[fr * 2],        sn0 = tr[fr * 2 + 1];
          float cs1 = tr[32 + fr * 2],   sn1 = tr[32 + fr * 2 + 1];
          float lo0 = acc[m][0][i], hi0 = acc[m][2][i];
          acc[m][0][i] = (lo0 * cs0 - hi0 * sn0) * qs;
          acc[m][2][i] = (hi0 * cs0 + lo0 * sn0) * qs;
          float lo1 = acc[m][1][i], hi1 = acc[m][3][i];
          acc[m][1][i] = (lo1 * cs1 - hi1 * sn1) * qs;
          acc[m][3][i] = (hi1 * cs1 + lo1 * sn1) * qs;
        }
    }
  }

  // epilogue: D col = lane&15, row = (lane>>4)*4 + i
#pragma unroll
  for (int m = 0; m < 4; m++) {
#pragma unroll
    for (int i = 0; i < 4; i++) {
      int row = row0 + wr * 64 + m * 16 + fq * 4 + i;
      if (BF16_OUT) {
        ushort* C = (ushort*)Cv;
#pragma unroll
        for (int n = 0; n < 4; n++)
          C[(size_t)row * N + col0 + wc * 64 + n * 16 + fr] = (ushort)f2b(acc[m][n][i]);
      } else {
        float* C = (float*)Cv;
#pragma unroll
        for (int n = 0; n < 4; n++)
          C[(size_t)row * N + col0 + wc * 64 + n * 16 + fr] = acc[m][n][i];
      }
    }
  }
}

// ---------------- Flash attention (non-causal, GQA 4:1) ----------------
// KVBLK=128, single-buffer __syncthreads loop (verified lane). K staged in LDS;
// V fragments read DIRECTLY from global (Vt is 256KB/head -> L2-resident;
// LDS staging of V was pure overhead per guide common-mistake #7).
// P: 4KB/wave (both qi), written then one PV pass sharing vf regs across qi.
// LDS 32KB; launch_bounds(256,4) caps VGPR at 128 for 16 waves/CU.
__global__ __launch_bounds__(256, 4) void k_attn(const ushort* __restrict__ QKV,
                                                 const ushort* __restrict__ Vt,
                                                 ushort* __restrict__ O) {
  __shared__ __align__(16) char ldsK[16384];     // 128 rows x 128B
  __shared__ __align__(16) char ldsP[4][4096];   // per-wave 2 qi x 16 rows x 128B
  int bx = blockIdx.x, by = blockIdx.y;
  swz8(bx, by);
  int tid = threadIdx.x, lane = tid & 63, wid = tid >> 6;
  int bh = by, b = bh >> 5, h = bh & 31, kv = h >> 2;
  int fr = lane & 15, fq = lane >> 4;
  int q0 = bx * 128 + wid * 32;

  // Q fragments (2 groups of 16 rows) — pre-scaled by gemm1, plain copy
  s16x8 qf[2][2];
#pragma unroll
  for (int kk = 0; kk < 2; kk++)
#pragma unroll
    for (int qi = 0; qi < 2; qi++)
      qf[kk][qi] = *(const s16x8*)(QKV + (size_t)(b * SS + q0 + qi * 16 + fr) * NQKVC
                                   + h * 64 + kk * 32 + fq * 8);

  const f32x4 fz = {0.f, 0.f, 0.f, 0.f};
  f32x4 o[4][2];
  f32x4 psum[2] = {fz, fz};
#pragma unroll
  for (int n = 0; n < 4; n++) { o[n][0] = fz; o[n][1] = fz; }
  const short ONE = 0x3F80;
  const s16x8 ones = {ONE, ONE, ONE, ONE, ONE, ONE, ONE, ONE};

  int rl = lane >> 3;
  int cbs = ((lane & 7) << 4) ^ (rl << 4);
  const char* Kbase = (const char*)QKV + (size_t)(b * SS) * (NQKVC * 2) + (size_t)(2048 + kv * 64) * 2;
  const ushort* Vg = Vt + (size_t)((b * 8 + kv) * 64) * SS;   // [64 d][SS s]
  char* pw = ldsP[wid];
  int pswz = (fr & 7) << 4;

  for (int t = 0; t < SS / 128; t++) {
    // stage K: 128 rows, each wave 32 rows
#pragma unroll
    for (int j = 0; j < 4; j++) {
      int rr = wid * 32 + j * 8;
      gld16(Kbase + (size_t)(t * 128 + rr + rl) * (NQKVC * 2) + cbs, ldsK + rr * 128);
    }
    __syncthreads();

#pragma unroll
    for (int hh = 0; hh < 2; hh++) {
      const char* Kc = ldsK + hh * 8192;
      int sbase = t * 128 + hh * 64;

      // S^T = K Q^T for both q-groups; kf shared
      f32x4 sf[4][2];
#pragma unroll
      for (int n = 0; n < 4; n++) { sf[n][0] = fz; sf[n][1] = fz; }
#pragma unroll
      for (int kk = 0; kk < 2; kk++) {
        int cb = kk * 64 + (fq << 4);
#pragma unroll
        for (int n = 0; n < 4; n++) {
          s16x8 kf = ldsfrag(Kc, n * 16 + fr, cb);
          sf[n][0] = mfma16(kf, qf[kk][0], sf[n][0]);
          sf[n][1] = mfma16(kf, qf[kk][1], sf[n][1]);
        }
      }

      // P = exp2(sf) for BOTH qi -> bf16 -> LDS (4KB/wave)
#pragma unroll
      for (int qi = 0; qi < 2; qi++) {
        char* pwr = pw + qi * 2048 + fr * 128;
#pragma unroll
        for (int n = 0; n < 4; n++) {
          float e0 = __builtin_amdgcn_exp2f(sf[n][qi][0]);
          float e1 = __builtin_amdgcn_exp2f(sf[n][qi][1]);
          float e2 = __builtin_amdgcn_exp2f(sf[n][qi][2]);
          float e3 = __builtin_amdgcn_exp2f(sf[n][qi][3]);
          unsigned u01, u23;
          asm("v_cvt_pk_bf16_f32 %0, %1, %2" : "=v"(u01) : "v"(e0), "v"(e1));
          asm("v_cvt_pk_bf16_f32 %0, %1, %2" : "=v"(u23) : "v"(e2), "v"(e3));
          u32x2 w = {u01, u23};
          *(u32x2*)(pwr + ((n * 32 + fq * 8) ^ pswz)) = w;
        }
      }
      asm volatile("" ::: "memory");

      // PV + row-sums; vf from GLOBAL (L2), shared across qi in registers
#pragma unroll
      for (int kk = 0; kk < 2; kk++) {
        int cb = kk * 64 + (fq << 4);
        int sc = sbase + kk * 32 + fq * 8;
        s16x8 vf0 = *(const s16x8*)(Vg + (size_t)(0 * 16 + fr) * SS + sc);
        s16x8 vf1 = *(const s16x8*)(Vg + (size_t)(1 * 16 + fr) * SS + sc);
        s16x8 vf2 = *(const s16x8*)(Vg + (size_t)(2 * 16 + fr) * SS + sc);
        s16x8 vf3 = *(const s16x8*)(Vg + (size_t)(3 * 16 + fr) * SS + sc);
        s16x8 pa0 = ldsfrag(pw, fr, cb);
        s16x8 pa1 = ldsfrag(pw + 2048, fr, cb);
        psum[0] = mfma16(pa0, ones, psum[0]);
        psum[1] = mfma16(pa1, ones, psum[1]);
        o[0][0] = mfma16(pa0, vf0, o[0][0]);  o[0][1] = mfma16(pa1, vf0, o[0][1]);
        o[1][0] = mfma16(pa0, vf1, o[1][0]);  o[1][1] = mfma16(pa1, vf1, o[1][1]);
        o[2][0] = mfma16(pa0, vf2, o[2][0]);  o[2][1] = mfma16(pa1, vf2, o[2][1]);
        o[3][0] = mfma16(pa0, vf3, o[3][0]);  o[3][1] = mfma16(pa1, vf3, o[3][1]);
      }
      asm volatile("" ::: "memory");
    }
    __syncthreads();
  }

  // normalize + store via per-wave LDS staging, one 16-row group at a time
#pragma unroll
  for (int qi = 0; qi < 2; qi++) {
    float inv[4];
#pragma unroll
    for (int i = 0; i < 4; i++) inv[i] = 1.0f / psum[qi][i];
#pragma unroll
    for (int n = 0; n < 4; n++) {
      float e0 = o[n][qi][0] * inv[0], e1 = o[n][qi][1] * inv[1];
      float e2 = o[n][qi][2] * inv[2], e3 = o[n][qi][3] * inv[3];
      unsigned u01, u23;
      asm("v_cvt_pk_bf16_f32 %0, %1, %2" : "=v"(u01) : "v"(e0), "v"(e1));
      asm("v_cvt_pk_bf16_f32 %0, %1, %2" : "=v"(u23) : "v"(e2), "v"(e3));
      int colb = n * 32 + fr * 2;
#pragma unroll
      for (int i = 0; i < 4; i++) {
        int r = fq * 4 + i;
        unsigned v16 = (i == 0) ? (u01 & 0xffffu) : (i == 1) ? (u01 >> 16)
                      : (i == 2) ? (u23 & 0xffffu) : (u23 >> 16);
        *(short*)(pw + r * 128 + (colb ^ ((r & 7) << 4))) = (short)v16;
      }
    }
    asm volatile("" ::: "memory");
    int orow = lane >> 2;
    int cbase = (lane & 3) * 32;
    int swo = (orow & 7) << 4;
    s16x8 ov0 = *(const s16x8*)(pw + orow * 128 + (cbase ^ swo));
    s16x8 ov1 = *(const s16x8*)(pw + orow * 128 + ((cbase + 16) ^ swo));
    ushort* dst = O + (size_t)(b * SS + bx * 128 + wid * 32 + qi * 16 + orow) * DM + h * 64 + (lane & 3) * 16;
    *(s16x8*)(dst)     = ov0;
    *(s16x8*)(dst + 8) = ov1;
    asm volatile("" ::: "memory");
  }
}

// ---------------- launcher ----------------
extern "C" void kernel_launch(void* const* d_in, const int* in_sizes, int n_in,
                              void* d_out, int out_size, void* d_ws, size_t ws_size,
                              hipStream_t stream) {
  const float* x  = (const float*)d_in[0];
  const float* Wq = (const float*)d_in[1];
  const float* Wk = (const float*)d_in[2];
  const float* Wv = (const float*)d_in[3];
  const float* Wo = (const float*)d_in[4];
  char* ws = (char*)d_ws;
  ushort* xb    = (ushort*)(ws);                         // 16 MB : x bf16 [4096][2048]
  ushort* Wqkvt = (ushort*)(ws + 16777216);              // 12 MB : [3072][2048]
  ushort* Wot   = (ushort*)(ws + 29360128);              //  8 MB : [2048][2048]
  ushort* QKV   = (ushort*)(ws + 37748736);              // 24 MB : [4096][3072]
  ushort* Vt    = (ushort*)(ws + 62914560);              //  4 MB : [1024][2048]
  ushort* Obuf  = (ushort*)(ws + 67108864);              // 16 MB : [4096][2048]
  // RoPE table (512 KB): ws tail if it fits, else d_out (overwritten later by gemm2)
  float* rtab = (ws_size >= (size_t)83886080 + 524288)
              ? (float*)(ws + 83886080) : (float*)d_out;

  k_wpre<<<18688, 256, 0, stream>>>(x, Wq, Wk, Wv, Wo, xb, Wqkvt, Wot, rtab);
  k_gemm<1, 1><<<dim3(24, 32), 256, 0, stream>>>(xb, Wqkvt, (void*)QKV, rtab, Vt, MT, NQKVC, DM);
  k_attn<<<dim3(16, 64), 256, 0, stream>>>(QKV, Vt, Obuf);
  k_gemm<0, 0><<<dim3(16, 32), 256, 0, stream>>>(Obuf, Wot, d_out, nullptr, nullptr, MT, DM, DM);
}

// Round 16
// 238.990 us; speedup vs baseline: 1.1998x; 1.1998x over previous
//
#include <hip/hip_runtime.h>
#include <hip/hip_bf16.h>
#include <stdint.h>

#define SS    2048      // sequence length
#define BB    2         // batch
#define MT    4096      // B*S rows
#define DM    2048      // d_model
#define NQKVC 3072      // fused QKV output cols: 2048 Q + 512 K + 512 V

typedef __attribute__((ext_vector_type(8))) short s16x8;
typedef __attribute__((ext_vector_type(4))) short s16x4;
typedef __attribute__((ext_vector_type(4))) float f32x4;
typedef __attribute__((ext_vector_type(2))) unsigned u32x2;

typedef __attribute__((address_space(1))) const void* as1cv;
typedef __attribute__((address_space(3))) void* as3v;

__device__ __forceinline__ float b2f(int u) {
  union { unsigned u; float f; } x; x.u = ((unsigned)(u & 0xFFFF)) << 16; return x.f;
}
__device__ __forceinline__ short f2b(float f) {
  union { float f; unsigned u; } x; x.f = f;
  unsigned r = x.u + 0x7FFFu + ((x.u >> 16) & 1u);
  return (short)(r >> 16);
}
// async global->LDS, 16B per lane. Dest is wave-uniform base; HW adds lane*16.
__device__ __forceinline__ void gld16(const void* g, void* l) {
  __builtin_amdgcn_global_load_lds((as1cv)(uintptr_t)g, (as3v)(uint32_t)(uintptr_t)l, 16, 0, 0);
}
// swizzled LDS tile read: rows of 128B, byte ^= (row&7)<<4
__device__ __forceinline__ s16x8 ldsfrag(const char* tile, int r, int cb) {
  return *(const s16x8*)(tile + r * 128 + (cb ^ ((r & 7) << 4)));
}
__device__ __forceinline__ f32x4 mfma16(s16x8 a, s16x8 b, f32x4 c) {
  return __builtin_amdgcn_mfma_f32_16x16x32_bf16(a, b, c, 0, 0, 0);
}
// bijective XCD-chunking swizzle (requires gridDim.x*gridDim.y % 8 == 0)
__device__ __forceinline__ void swz8(int& bx, int& by) {
  int gx = gridDim.x;
  int lin = by * gx + bx;
  int tot = gx * gridDim.y;
  int s = (lin & 7) * (tot >> 3) + (lin >> 3);
  bx = s % gx;
  by = s / gx;
}

// ---------------- merged prep: x->bf16, 4 weight transposes, RoPE table ----------------
// blocks [0,8192): xcvt  [8192,12288): Wq  [12288,13312): Wk  [13312,14336): Wv
//        [14336,18432): Wo  [18432,18688): rtab
__global__ __launch_bounds__(256) void k_wpre(const float* __restrict__ x,
                                              const float* __restrict__ Wq,
                                              const float* __restrict__ Wk,
                                              const float* __restrict__ Wv,
                                              const float* __restrict__ Wo,
                                              ushort* __restrict__ xb,
                                              ushort* __restrict__ Wqkvt,
                                              ushort* __restrict__ Wot,
                                              float* __restrict__ rtab) {
  __shared__ float t[32][33];
  int bid = blockIdx.x;
  if (bid < 8192) {
    int i = (bid * 256 + threadIdx.x) * 4;
    float4 v = *(const float4*)(x + i);
    s16x4 o = { f2b(v.x), f2b(v.y), f2b(v.z), f2b(v.w) };
    *(s16x4*)(xb + i) = o;
    return;
  }
  bid -= 8192;
  if (bid >= 10240) {
    int idx = (bid - 10240) * 256 + threadIdx.x;   // s*32 + d
    int d = idx & 31, s = idx >> 5;
    float invf = exp2f(-(float)d * (18.931568569324174f / 32.0f));
    float sn, c;
    sincosf((float)s * invf, &sn, &c);
    rtab[idx * 2]     = c;
    rtab[idx * 2 + 1] = sn;
    return;
  }
  const float* W; ushort* out; int N; int l;
  if (bid < 4096)      { W = Wq; out = Wqkvt;                         N = 2048; l = bid; }
  else if (bid < 5120) { W = Wk; out = Wqkvt + (size_t)2048 * 2048;   N = 512;  l = bid - 4096; }
  else if (bid < 6144) { W = Wv; out = Wqkvt + (size_t)2560 * 2048;   N = 512;  l = bid - 5120; }
  else                 { W = Wo; out = Wot;                           N = 2048; l = bid - 6144; }
  int k0 = (l & 63) * 32, n0 = (l >> 6) * 32;
  int tx = threadIdx.x & 31, ty = threadIdx.x >> 5;
#pragma unroll
  for (int j = 0; j < 32; j += 8)
    t[ty + j][tx] = W[(size_t)(k0 + ty + j) * N + n0 + tx];
  __syncthreads();
  // vectorized transposed store: ushort2 per thread, 2 iterations
  int tx2 = threadIdx.x & 15, rr = threadIdx.x >> 4;   // rr in [0,16)
#pragma unroll
  for (int j = 0; j < 32; j += 16) {
    int nl = rr + j;
    ushort2 w;
    w.x = (ushort)f2b(t[tx2 * 2][nl]);
    w.y = (ushort)f2b(t[tx2 * 2 + 1][nl]);
    *(ushort2*)(out + (size_t)(n0 + nl) * 2048 + k0 + tx2 * 2) = w;
  }
}

// ---------------- GEMM: C[M][N] = A[M][K] * B^T (B is [N][K]), all bf16, fp32 acc ----------------
// 128x128 tile, BK=64, 4 waves (2x2), each wave 64x64 = 4x4 frags of 16x16x32 MFMA.
// ROPE=1: rotary embedding on Q/K bands in the fp32 epilogue via the precomputed table;
// Q band pre-scaled by 0.125*log2(e). V band (col0 >= 2560) writes TRANSPOSED to Vt
// via LDS staging (fuses the old k_vt kernel) and skips the C write.
template <int BF16_OUT, int ROPE>
__global__ __launch_bounds__(256) void k_gemm(const ushort* __restrict__ A,
                                              const ushort* __restrict__ B,
                                              void* __restrict__ Cv,
                                              const float* __restrict__ rtab,
                                              ushort* __restrict__ Vt,
                                              int M, int N, int K) {
  __shared__ __align__(16) char lds[32768];
  char* ldsA = lds;
  char* ldsB = lds + 16384;
  int bx = blockIdx.x, by = blockIdx.y;
  swz8(bx, by);
  int tid = threadIdx.x, lane = tid & 63, wid = tid >> 6;
  int wr = wid >> 1, wc = wid & 1;
  int row0 = by * 128, col0 = bx * 128;
  int fr = lane & 15, fq = lane >> 4;
  f32x4 acc[4][4] = {};
  int rl = lane >> 3;                                   // row within 8-row chunk
  int cbs = ((lane & 7) << 4) ^ (rl << 4);              // pre-swizzled source byte-in-row
  const char* Ab = (const char*)A;
  const char* Bb = (const char*)B;
  size_t ldb = (size_t)K * 2;

  for (int kt = 0; kt < K; kt += 64) {
#pragma unroll
    for (int i = 0; i < 4; i++) {
      int ra = wid * 32 + i * 8 + rl;
      gld16(Ab + (size_t)(row0 + ra) * ldb + (size_t)kt * 2 + cbs,
            ldsA + (wid * 32 + i * 8) * 128);
      gld16(Bb + (size_t)(col0 + ra) * ldb + (size_t)kt * 2 + cbs,
            ldsB + (wid * 32 + i * 8) * 128);
    }
    __syncthreads();
#pragma unroll
    for (int kk = 0; kk < 2; kk++) {
      int cb = kk * 64 + (fq << 4);
      s16x8 af[4], bg[4];
#pragma unroll
      for (int m = 0; m < 4; m++) af[m] = ldsfrag(ldsA, wr * 64 + m * 16 + fr, cb);
#pragma unroll
      for (int n = 0; n < 4; n++) bg[n] = ldsfrag(ldsB, wc * 64 + n * 16 + fr, cb);
#pragma unroll
      for (int m = 0; m < 4; m++)
#pragma unroll
        for (int n = 0; n < 4; n++)
          acc[m][n] = mfma16(af[m], bg[n], acc[m][n]);
    }
    __syncthreads();
  }

  int cb0 = col0 + wc * 64;              // 64-col wave band

  if (ROPE && col0 >= 2560) {
    // ---- V band: transpose to Vt[b*512 + (c-2560)][s] via LDS, skip C write ----
    __syncthreads();                     // all waves done reading ldsA/B
    char* tw = lds + wid * 8192;         // per-wave [64 col][64 s] bf16, swizzled rows of 128B
#pragma unroll
    for (int m = 0; m < 4; m++)
#pragma unroll
      for (int n = 0; n < 4; n++) {
        int cl = n * 16 + fr;
        unsigned u01, u23;
        asm("v_cvt_pk_bf16_f32 %0, %1, %2" : "=v"(u01) : "v"(acc[m][n][0]), "v"(acc[m][n][1]));
        asm("v_cvt_pk_bf16_f32 %0, %1, %2" : "=v"(u23) : "v"(acc[m][n][2]), "v"(acc[m][n][3]));
        u32x2 w = {u01, u23};
        *(u32x2*)(tw + cl * 128 + (((m * 16 + fq * 4) * 2) ^ ((cl & 7) << 4))) = w;
      }
    asm volatile("" ::: "memory");
    int b = row0 >> 11;                  // batch index (blocks never straddle b)
    int s0 = row0 - b * 2048 + wr * 64;  // this wave's 64 s-rows
    int vrow0 = b * 512 + (cb0 - 2560);
#pragma unroll
    for (int jj = 0; jj < 8; jj++) {
      int cl = jj * 8 + (lane >> 3);
      int ch = lane & 7;
      s16x8 v = *(const s16x8*)(tw + cl * 128 + ((ch * 16) ^ ((cl & 7) << 4)));
      *(s16x8*)(Vt + (size_t)(vrow0 + cl) * SS + s0 + ch * 8) = v;
    }
    return;
  }

  if (ROPE) {
    if (cb0 < 2560) {                    // Q band (<2048) or K band (2048..2559)
      float qs = (cb0 < 2048) ? 0.18033688011112042f : 1.0f;
#pragma unroll
      for (int m = 0; m < 4; m++)
#pragma unroll
        for (int i = 0; i < 4; i++) {
          int srow = (row0 + wr * 64 + m * 16 + fq * 4 + i) & (SS - 1);
          const float* tr = rtab + srow * 64;
          float cs0 = tr[fr * 2],        sn0 = tr[fr * 2 + 1];
          float cs1 = tr[32 + fr * 2],   sn1 = tr[32 + fr * 2 + 1];
          float lo0 = acc[m][0][i], hi0 = acc[m][2][i];
          acc[m][0][i] = (lo0 * cs0 - hi0 * sn0) * qs;
          acc[m][2][i] = (hi0 * cs0 + lo0 * sn0) * qs;
          float lo1 = acc[m][1][i], hi1 = acc[m][3][i];
          acc[m][1][i] = (lo1 * cs1 - hi1 * sn1) * qs;
          acc[m][3][i] = (hi1 * cs1 + lo1 * sn1) * qs;
        }
    }
  }

  // epilogue: D col = lane&15, row = (lane>>4)*4 + i
#pragma unroll
  for (int m = 0; m < 4; m++) {
#pragma unroll
    for (int i = 0; i < 4; i++) {
      int row = row0 + wr * 64 + m * 16 + fq * 4 + i;
      if (BF16_OUT) {
        ushort* C = (ushort*)Cv;
#pragma unroll
        for (int n = 0; n < 4; n++)
          C[(size_t)row * N + col0 + wc * 64 + n * 16 + fr] = (ushort)f2b(acc[m][n][i]);
      } else {
        float* C = (float*)Cv;
#pragma unroll
        for (int n = 0; n < 4; n++)
          C[(size_t)row * N + col0 + wc * 64 + n * 16 + fr] = acc[m][n][i];
      }
    }
  }
}

// ---------------- Flash attention (non-causal, GQA 4:1) ----------------
// Verified structure, KVBLK=128 (two 64-row sub-tiles per barrier round).
// Per-wave 2K P buffer, sequential qi. Q arrives pre-scaled from gemm1.
// LDS 40KB -> 4 blocks/CU. Single-buffer __syncthreads only (verified lane).
__global__ __launch_bounds__(256) void k_attn(const ushort* __restrict__ QKV,
                                              const ushort* __restrict__ Vt,
                                              ushort* __restrict__ O) {
  __shared__ __align__(16) char ldsK[16384];     // 128 rows x 128B
  __shared__ __align__(16) char ldsV[16384];     // 2 subtiles x 64 d-rows x 128B
  __shared__ __align__(16) char ldsP[4][2048];   // per-wave 16 rows x 128B (one qi at a time)
  int bx = blockIdx.x, by = blockIdx.y;
  swz8(bx, by);
  int tid = threadIdx.x, lane = tid & 63, wid = tid >> 6;
  int bh = by, b = bh >> 5, h = bh & 31, kv = h >> 2;
  int fr = lane & 15, fq = lane >> 4;
  int q0 = bx * 128 + wid * 32;

  // Q fragments (2 groups of 16 rows) — pre-scaled by gemm1, plain copy
  s16x8 qf[2][2];
#pragma unroll
  for (int kk = 0; kk < 2; kk++)
#pragma unroll
    for (int qi = 0; qi < 2; qi++)
      qf[kk][qi] = *(const s16x8*)(QKV + (size_t)(b * SS + q0 + qi * 16 + fr) * NQKVC
                                   + h * 64 + kk * 32 + fq * 8);

  const f32x4 fz = {0.f, 0.f, 0.f, 0.f};
  f32x4 o[4][2];
  f32x4 psum[2] = {fz, fz};
#pragma unroll
  for (int n = 0; n < 4; n++) { o[n][0] = fz; o[n][1] = fz; }
  const short ONE = 0x3F80;
  const s16x8 ones = {ONE, ONE, ONE, ONE, ONE, ONE, ONE, ONE};

  int rl = lane >> 3;
  int cbs = ((lane & 7) << 4) ^ (rl << 4);
  const char* Kbase = (const char*)QKV + (size_t)(b * SS) * (NQKVC * 2) + (size_t)(2048 + kv * 64) * 2;
  const char* Vbase = (const char*)Vt + (size_t)((b * 8 + kv) * 64) * (SS * 2);
  char* pw = ldsP[wid];
  int pswz = (fr & 7) << 4;

  for (int t = 0; t < SS / 128; t++) {
    // stage K: 128 rows, each wave 32 rows
#pragma unroll
    for (int j = 0; j < 4; j++) {
      int rr = wid * 32 + j * 8;
      gld16(Kbase + (size_t)(t * 128 + rr + rl) * (NQKVC * 2) + cbs, ldsK + rr * 128);
    }
    // stage V: 2 subtiles (s-cols t*128+hh*64..+63) x 64 d-rows, each wave 16 rows/subtile
#pragma unroll
    for (int hh = 0; hh < 2; hh++)
#pragma unroll
      for (int j = 0; j < 2; j++) {
        int rr = wid * 16 + j * 8;
        gld16(Vbase + (size_t)(rr + rl) * (SS * 2) + (size_t)t * 256 + hh * 128 + cbs,
              ldsV + (hh * 64 + rr) * 128);
      }
    __syncthreads();

#pragma unroll
    for (int hh = 0; hh < 2; hh++) {
      const char* Kc = ldsK + hh * 8192;
      const char* Vc = ldsV + hh * 8192;

      // S^T = K Q^T for both q-groups; kf shared
      f32x4 sf[4][2];
#pragma unroll
      for (int n = 0; n < 4; n++) { sf[n][0] = fz; sf[n][1] = fz; }
#pragma unroll
      for (int kk = 0; kk < 2; kk++) {
        int cb = kk * 64 + (fq << 4);
#pragma unroll
        for (int n = 0; n < 4; n++) {
          s16x8 kf = ldsfrag(Kc, n * 16 + fr, cb);
          sf[n][0] = mfma16(kf, qf[kk][0], sf[n][0]);
          sf[n][1] = mfma16(kf, qf[kk][1], sf[n][1]);
        }
      }

      // per q-group: P = exp2(sf) -> bf16 -> LDS; then PV + row-sum; buffer reused
#pragma unroll
      for (int qi = 0; qi < 2; qi++) {
        char* pwr = pw + fr * 128;
#pragma unroll
        for (int n = 0; n < 4; n++) {
          float e0 = __builtin_amdgcn_exp2f(sf[n][qi][0]);
          float e1 = __builtin_amdgcn_exp2f(sf[n][qi][1]);
          float e2 = __builtin_amdgcn_exp2f(sf[n][qi][2]);
          float e3 = __builtin_amdgcn_exp2f(sf[n][qi][3]);
          unsigned u01, u23;
          asm("v_cvt_pk_bf16_f32 %0, %1, %2" : "=v"(u01) : "v"(e0), "v"(e1));
          asm("v_cvt_pk_bf16_f32 %0, %1, %2" : "=v"(u23) : "v"(e2), "v"(e3));
          u32x2 w = {u01, u23};
          *(u32x2*)(pwr + ((n * 32 + fq * 8) ^ pswz)) = w;
        }
        asm volatile("" ::: "memory");
#pragma unroll
        for (int kk = 0; kk < 2; kk++) {
          int cb = kk * 64 + (fq << 4);
          s16x8 pa = ldsfrag(pw, fr, cb);
          psum[qi] = mfma16(pa, ones, psum[qi]);
#pragma unroll
          for (int n = 0; n < 4; n++) {
            s16x8 vf = ldsfrag(Vc, n * 16 + fr, cb);
            o[n][qi] = mfma16(pa, vf, o[n][qi]);
          }
        }
        asm volatile("" ::: "memory");
      }
    }
    __syncthreads();
  }

  // normalize + store via per-wave LDS staging, one 16-row group at a time
#pragma unroll
  for (int qi = 0; qi < 2; qi++) {
    float inv[4];
#pragma unroll
    for (int i = 0; i < 4; i++) inv[i] = 1.0f / psum[qi][i];
#pragma unroll
    for (int n = 0; n < 4; n++) {
      float e0 = o[n][qi][0] * inv[0], e1 = o[n][qi][1] * inv[1];
      float e2 = o[n][qi][2] * inv[2], e3 = o[n][qi][3] * inv[3];
      unsigned u01, u23;
      asm("v_cvt_pk_bf16_f32 %0, %1, %2" : "=v"(u01) : "v"(e0), "v"(e1));
      asm("v_cvt_pk_bf16_f32 %0, %1, %2" : "=v"(u23) : "v"(e2), "v"(e3));
      int colb = n * 32 + fr * 2;
#pragma unroll
      for (int i = 0; i < 4; i++) {
        int r = fq * 4 + i;
        unsigned v16 = (i == 0) ? (u01 & 0xffffu) : (i == 1) ? (u01 >> 16)
                      : (i == 2) ? (u23 & 0xffffu) : (u23 >> 16);
        *(short*)(pw + r * 128 + (colb ^ ((r & 7) << 4))) = (short)v16;
      }
    }
    asm volatile("" ::: "memory");
    int orow = lane >> 2;
    int cbase = (lane & 3) * 32;
    int swo = (orow & 7) << 4;
    s16x8 ov0 = *(const s16x8*)(pw + orow * 128 + (cbase ^ swo));
    s16x8 ov1 = *(const s16x8*)(pw + orow * 128 + ((cbase + 16) ^ swo));
    ushort* dst = O + (size_t)(b * SS + bx * 128 + wid * 32 + qi * 16 + orow) * DM + h * 64 + (lane & 3) * 16;
    *(s16x8*)(dst)     = ov0;
    *(s16x8*)(dst + 8) = ov1;
    asm volatile("" ::: "memory");
  }
}

// ---------------- launcher ----------------
extern "C" void kernel_launch(void* const* d_in, const int* in_sizes, int n_in,
                              void* d_out, int out_size, void* d_ws, size_t ws_size,
                              hipStream_t stream) {
  const float* x  = (const float*)d_in[0];
  const float* Wq = (const float*)d_in[1];
  const float* Wk = (const float*)d_in[2];
  const float* Wv = (const float*)d_in[3];
  const float* Wo = (const float*)d_in[4];
  char* ws = (char*)d_ws;
  ushort* xb    = (ushort*)(ws);                         // 16 MB : x bf16 [4096][2048]
  ushort* Wqkvt = (ushort*)(ws + 16777216);              // 12 MB : [3072][2048]
  ushort* Wot   = (ushort*)(ws + 29360128);              //  8 MB : [2048][2048]
  ushort* QKV   = (ushort*)(ws + 37748736);              // 24 MB : [4096][3072]
  ushort* Vt    = (ushort*)(ws + 62914560);              //  4 MB : [1024][2048]
  ushort* Obuf  = (ushort*)(ws + 67108864);              // 16 MB : [4096][2048]
  // RoPE table (512 KB): ws tail if it fits, else d_out (overwritten later by gemm2)
  float* rtab = (ws_size >= (size_t)83886080 + 524288)
              ? (float*)(ws + 83886080) : (float*)d_out;

  k_wpre<<<18688, 256, 0, stream>>>(x, Wq, Wk, Wv, Wo, xb, Wqkvt, Wot, rtab);
  k_gemm<1, 1><<<dim3(24, 32), 256, 0, stream>>>(xb, Wqkvt, (void*)QKV, rtab, Vt, MT, NQKVC, DM);
  k_attn<<<dim3(16, 64), 256, 0, stream>>>(QKV, Vt, Obuf);
  k_gemm<0, 0><<<dim3(16, 32), 256, 0, stream>>>(Obuf, Wot, d_out, nullptr, nullptr, MT, DM, DM);
}

// Round 17
// 238.659 us; speedup vs baseline: 1.2014x; 1.0014x over previous
//
#include <hip/hip_runtime.h>
#include <hip/hip_bf16.h>
#include <stdint.h>

#define SS    2048      // sequence length
#define BB    2         // batch
#define MT    4096      // B*S rows
#define DM    2048      // d_model
#define NQKVC 3072      // fused QKV output cols: 2048 Q + 512 K + 512 V

typedef __attribute__((ext_vector_type(8))) short s16x8;
typedef __attribute__((ext_vector_type(4))) short s16x4;
typedef __attribute__((ext_vector_type(4))) float f32x4;
typedef __attribute__((ext_vector_type(2))) unsigned u32x2;

typedef __attribute__((address_space(1))) const void* as1cv;
typedef __attribute__((address_space(3))) void* as3v;

__device__ __forceinline__ float b2f(int u) {
  union { unsigned u; float f; } x; x.u = ((unsigned)(u & 0xFFFF)) << 16; return x.f;
}
__device__ __forceinline__ short f2b(float f) {
  union { float f; unsigned u; } x; x.f = f;
  unsigned r = x.u + 0x7FFFu + ((x.u >> 16) & 1u);
  return (short)(r >> 16);
}
// async global->LDS, 16B per lane. Dest is wave-uniform base; HW adds lane*16.
__device__ __forceinline__ void gld16(const void* g, void* l) {
  __builtin_amdgcn_global_load_lds((as1cv)(uintptr_t)g, (as3v)(uint32_t)(uintptr_t)l, 16, 0, 0);
}
// swizzled LDS tile read: rows of 128B, byte ^= (row&7)<<4
__device__ __forceinline__ s16x8 ldsfrag(const char* tile, int r, int cb) {
  return *(const s16x8*)(tile + r * 128 + (cb ^ ((r & 7) << 4)));
}
__device__ __forceinline__ f32x4 mfma16(s16x8 a, s16x8 b, f32x4 c) {
  return __builtin_amdgcn_mfma_f32_16x16x32_bf16(a, b, c, 0, 0, 0);
}
// bijective XCD-chunking swizzle (requires gridDim.x*gridDim.y % 8 == 0)
__device__ __forceinline__ void swz8(int& bx, int& by) {
  int gx = gridDim.x;
  int lin = by * gx + bx;
  int tot = gx * gridDim.y;
  int s = (lin & 7) * (tot >> 3) + (lin >> 3);
  bx = s % gx;
  by = s / gx;
}

// ---------------- merged prep: x->bf16, 4 weight transposes, RoPE table ----------------
// blocks [0,8192): xcvt  [8192,12288): Wq  [12288,13312): Wk  [13312,14336): Wv
//        [14336,18432): Wo  [18432,18688): rtab
__global__ __launch_bounds__(256) void k_wpre(const float* __restrict__ x,
                                              const float* __restrict__ Wq,
                                              const float* __restrict__ Wk,
                                              const float* __restrict__ Wv,
                                              const float* __restrict__ Wo,
                                              ushort* __restrict__ xb,
                                              ushort* __restrict__ Wqkvt,
                                              ushort* __restrict__ Wot,
                                              float* __restrict__ rtab) {
  __shared__ float t[32][33];
  int bid = blockIdx.x;
  if (bid < 8192) {
    int i = (bid * 256 + threadIdx.x) * 4;
    float4 v = *(const float4*)(x + i);
    s16x4 o = { f2b(v.x), f2b(v.y), f2b(v.z), f2b(v.w) };
    *(s16x4*)(xb + i) = o;
    return;
  }
  bid -= 8192;
  if (bid >= 10240) {
    int idx = (bid - 10240) * 256 + threadIdx.x;   // s*32 + d
    int d = idx & 31, s = idx >> 5;
    float invf = exp2f(-(float)d * (18.931568569324174f / 32.0f));
    float sn, c;
    sincosf((float)s * invf, &sn, &c);
    rtab[idx * 2]     = c;
    rtab[idx * 2 + 1] = sn;
    return;
  }
  const float* W; ushort* out; int N; int l;
  if (bid < 4096)      { W = Wq; out = Wqkvt;                         N = 2048; l = bid; }
  else if (bid < 5120) { W = Wk; out = Wqkvt + (size_t)2048 * 2048;   N = 512;  l = bid - 4096; }
  else if (bid < 6144) { W = Wv; out = Wqkvt + (size_t)2560 * 2048;   N = 512;  l = bid - 5120; }
  else                 { W = Wo; out = Wot;                           N = 2048; l = bid - 6144; }
  int k0 = (l & 63) * 32, n0 = (l >> 6) * 32;
  int tx = threadIdx.x & 31, ty = threadIdx.x >> 5;
#pragma unroll
  for (int j = 0; j < 32; j += 8)
    t[ty + j][tx] = W[(size_t)(k0 + ty + j) * N + n0 + tx];
  __syncthreads();
  // vectorized transposed store: ushort2 per thread, 2 iterations
  int tx2 = threadIdx.x & 15, rr = threadIdx.x >> 4;   // rr in [0,16)
#pragma unroll
  for (int j = 0; j < 32; j += 16) {
    int nl = rr + j;
    ushort2 w;
    w.x = (ushort)f2b(t[tx2 * 2][nl]);
    w.y = (ushort)f2b(t[tx2 * 2 + 1][nl]);
    *(ushort2*)(out + (size_t)(n0 + nl) * 2048 + k0 + tx2 * 2) = w;
  }
}

// ---------------- GEMM: C[M][N] = A[M][K] * B^T (B is [N][K]), all bf16, fp32 acc ----------------
// 128x128 tile, BK=64, 4 waves (2x2), each wave 64x64 = 4x4 frags of 16x16x32 MFMA.
// ROPE=1: rotary embedding on Q/K bands in the fp32 epilogue via the precomputed table;
// Q band pre-scaled by 0.125*log2(e). V band (col0 >= 2560) writes TRANSPOSED to Vt
// via LDS staging (fuses the old k_vt kernel) and skips the C write.
template <int BF16_OUT, int ROPE>
__global__ __launch_bounds__(256) void k_gemm(const ushort* __restrict__ A,
                                              const ushort* __restrict__ B,
                                              void* __restrict__ Cv,
                                              const float* __restrict__ rtab,
                                              ushort* __restrict__ Vt,
                                              int M, int N, int K) {
  __shared__ __align__(16) char lds[32768];
  char* ldsA = lds;
  char* ldsB = lds + 16384;
  int bx = blockIdx.x, by = blockIdx.y;
  swz8(bx, by);
  int tid = threadIdx.x, lane = tid & 63, wid = tid >> 6;
  int wr = wid >> 1, wc = wid & 1;
  int row0 = by * 128, col0 = bx * 128;
  int fr = lane & 15, fq = lane >> 4;
  f32x4 acc[4][4] = {};
  int rl = lane >> 3;                                   // row within 8-row chunk
  int cbs = ((lane & 7) << 4) ^ (rl << 4);              // pre-swizzled source byte-in-row
  const char* Ab = (const char*)A;
  const char* Bb = (const char*)B;
  size_t ldb = (size_t)K * 2;

  for (int kt = 0; kt < K; kt += 64) {
#pragma unroll
    for (int i = 0; i < 4; i++) {
      int ra = wid * 32 + i * 8 + rl;
      gld16(Ab + (size_t)(row0 + ra) * ldb + (size_t)kt * 2 + cbs,
            ldsA + (wid * 32 + i * 8) * 128);
      gld16(Bb + (size_t)(col0 + ra) * ldb + (size_t)kt * 2 + cbs,
            ldsB + (wid * 32 + i * 8) * 128);
    }
    __syncthreads();
#pragma unroll
    for (int kk = 0; kk < 2; kk++) {
      int cb = kk * 64 + (fq << 4);
      s16x8 af[4], bg[4];
#pragma unroll
      for (int m = 0; m < 4; m++) af[m] = ldsfrag(ldsA, wr * 64 + m * 16 + fr, cb);
#pragma unroll
      for (int n = 0; n < 4; n++) bg[n] = ldsfrag(ldsB, wc * 64 + n * 16 + fr, cb);
#pragma unroll
      for (int m = 0; m < 4; m++)
#pragma unroll
        for (int n = 0; n < 4; n++)
          acc[m][n] = mfma16(af[m], bg[n], acc[m][n]);
    }
    __syncthreads();
  }

  int cb0 = col0 + wc * 64;              // 64-col wave band

  if (ROPE && col0 >= 2560) {
    // ---- V band: transpose to Vt[b*512 + (c-2560)][s] via LDS, skip C write ----
    __syncthreads();                     // all waves done reading ldsA/B
    char* tw = lds + wid * 8192;         // per-wave [64 col][64 s] bf16, swizzled rows of 128B
#pragma unroll
    for (int m = 0; m < 4; m++)
#pragma unroll
      for (int n = 0; n < 4; n++) {
        int cl = n * 16 + fr;
        unsigned u01, u23;
        asm("v_cvt_pk_bf16_f32 %0, %1, %2" : "=v"(u01) : "v"(acc[m][n][0]), "v"(acc[m][n][1]));
        asm("v_cvt_pk_bf16_f32 %0, %1, %2" : "=v"(u23) : "v"(acc[m][n][2]), "v"(acc[m][n][3]));
        u32x2 w = {u01, u23};
        *(u32x2*)(tw + cl * 128 + (((m * 16 + fq * 4) * 2) ^ ((cl & 7) << 4))) = w;
      }
    asm volatile("" ::: "memory");
    int b = row0 >> 11;                  // batch index (blocks never straddle b)
    int s0 = row0 - b * 2048 + wr * 64;  // this wave's 64 s-rows
    int vrow0 = b * 512 + (cb0 - 2560);
#pragma unroll
    for (int jj = 0; jj < 8; jj++) {
      int cl = jj * 8 + (lane >> 3);
      int ch = lane & 7;
      s16x8 v = *(const s16x8*)(tw + cl * 128 + ((ch * 16) ^ ((cl & 7) << 4)));
      *(s16x8*)(Vt + (size_t)(vrow0 + cl) * SS + s0 + ch * 8) = v;
    }
    return;
  }

  if (ROPE) {
    if (cb0 < 2560) {                    // Q band (<2048) or K band (2048..2559)
      float qs = (cb0 < 2048) ? 0.18033688011112042f : 1.0f;
#pragma unroll
      for (int m = 0; m < 4; m++)
#pragma unroll
        for (int i = 0; i < 4; i++) {
          int srow = (row0 + wr * 64 + m * 16 + fq * 4 + i) & (SS - 1);
          const float* tr = rtab + srow * 64;
          float cs0 = tr[fr * 2],        sn0 = tr[fr * 2 + 1];
          float cs1 = tr[32 + fr * 2],   sn1 = tr[32 + fr * 2 + 1];
          float lo0 = acc[m][0][i], hi0 = acc[m][2][i];
          acc[m][0][i] = (lo0 * cs0 - hi0 * sn0) * qs;
          acc[m][2][i] = (hi0 * cs0 + lo0 * sn0) * qs;
          float lo1 = acc[m][1][i], hi1 = acc[m][3][i];
          acc[m][1][i] = (lo1 * cs1 - hi1 * sn1) * qs;
          acc[m][3][i] = (hi1 * cs1 + lo1 * sn1) * qs;
        }
    }
  }

  // epilogue: D col = lane&15, row = (lane>>4)*4 + i
#pragma unroll
  for (int m = 0; m < 4; m++) {
#pragma unroll
    for (int i = 0; i < 4; i++) {
      int row = row0 + wr * 64 + m * 16 + fq * 4 + i;
      if (BF16_OUT) {
        ushort* C = (ushort*)Cv;
#pragma unroll
        for (int n = 0; n < 4; n++)
          C[(size_t)row * N + col0 + wc * 64 + n * 16 + fr] = (ushort)f2b(acc[m][n][i]);
      } else {
        float* C = (float*)Cv;
#pragma unroll
        for (int n = 0; n < 4; n++)
          C[(size_t)row * N + col0 + wc * 64 + n * 16 + fr] = acc[m][n][i];
      }
    }
  }
}

// ---------------- Flash attention (non-causal, GQA 4:1) ----------------
// Verified structure, KVBLK=128 (two 64-row sub-tiles per barrier round).
// Per-wave 2K P buffer, sequential qi. Q arrives pre-scaled from gemm1.
// LDS 40KB -> 4 blocks/CU. Single-buffer __syncthreads only (verified lane).
// QK^T kk=0 uses C=0 directly (mfma writes sf; no per-subtile zero-fill movs).
__global__ __launch_bounds__(256) void k_attn(const ushort* __restrict__ QKV,
                                              const ushort* __restrict__ Vt,
                                              ushort* __restrict__ O) {
  __shared__ __align__(16) char ldsK[16384];     // 128 rows x 128B
  __shared__ __align__(16) char ldsV[16384];     // 2 subtiles x 64 d-rows x 128B
  __shared__ __align__(16) char ldsP[4][2048];   // per-wave 16 rows x 128B (one qi at a time)
  int bx = blockIdx.x, by = blockIdx.y;
  swz8(bx, by);
  int tid = threadIdx.x, lane = tid & 63, wid = tid >> 6;
  int bh = by, b = bh >> 5, h = bh & 31, kv = h >> 2;
  int fr = lane & 15, fq = lane >> 4;
  int q0 = bx * 128 + wid * 32;

  // Q fragments (2 groups of 16 rows) — pre-scaled by gemm1, plain copy
  s16x8 qf[2][2];
#pragma unroll
  for (int kk = 0; kk < 2; kk++)
#pragma unroll
    for (int qi = 0; qi < 2; qi++)
      qf[kk][qi] = *(const s16x8*)(QKV + (size_t)(b * SS + q0 + qi * 16 + fr) * NQKVC
                                   + h * 64 + kk * 32 + fq * 8);

  const f32x4 fz = {0.f, 0.f, 0.f, 0.f};
  f32x4 o[4][2];
  f32x4 psum[2] = {fz, fz};
#pragma unroll
  for (int n = 0; n < 4; n++) { o[n][0] = fz; o[n][1] = fz; }
  const short ONE = 0x3F80;
  const s16x8 ones = {ONE, ONE, ONE, ONE, ONE, ONE, ONE, ONE};

  int rl = lane >> 3;
  int cbs = ((lane & 7) << 4) ^ (rl << 4);
  const char* Kbase = (const char*)QKV + (size_t)(b * SS) * (NQKVC * 2) + (size_t)(2048 + kv * 64) * 2;
  const char* Vbase = (const char*)Vt + (size_t)((b * 8 + kv) * 64) * (SS * 2);
  char* pw = ldsP[wid];
  int pswz = (fr & 7) << 4;

  for (int t = 0; t < SS / 128; t++) {
    // stage K: 128 rows, each wave 32 rows
#pragma unroll
    for (int j = 0; j < 4; j++) {
      int rr = wid * 32 + j * 8;
      gld16(Kbase + (size_t)(t * 128 + rr + rl) * (NQKVC * 2) + cbs, ldsK + rr * 128);
    }
    // stage V: 2 subtiles (s-cols t*128+hh*64..+63) x 64 d-rows, each wave 16 rows/subtile
#pragma unroll
    for (int hh = 0; hh < 2; hh++)
#pragma unroll
      for (int j = 0; j < 2; j++) {
        int rr = wid * 16 + j * 8;
        gld16(Vbase + (size_t)(rr + rl) * (SS * 2) + (size_t)t * 256 + hh * 128 + cbs,
              ldsV + (hh * 64 + rr) * 128);
      }
    __syncthreads();

#pragma unroll
    for (int hh = 0; hh < 2; hh++) {
      const char* Kc = ldsK + hh * 8192;
      const char* Vc = ldsV + hh * 8192;

      // S^T = K Q^T for both q-groups; kf shared; kk=0 writes sf via C=0
      f32x4 sf[4][2];
      {
        int cb = (fq << 4);                       // kk = 0
#pragma unroll
        for (int n = 0; n < 4; n++) {
          s16x8 kf = ldsfrag(Kc, n * 16 + fr, cb);
          sf[n][0] = mfma16(kf, qf[0][0], fz);
          sf[n][1] = mfma16(kf, qf[0][1], fz);
        }
        cb = 64 + (fq << 4);                      // kk = 1
#pragma unroll
        for (int n = 0; n < 4; n++) {
          s16x8 kf = ldsfrag(Kc, n * 16 + fr, cb);
          sf[n][0] = mfma16(kf, qf[1][0], sf[n][0]);
          sf[n][1] = mfma16(kf, qf[1][1], sf[n][1]);
        }
      }

      // per q-group: P = exp2(sf) -> bf16 -> LDS; then PV + row-sum; buffer reused
#pragma unroll
      for (int qi = 0; qi < 2; qi++) {
        char* pwr = pw + fr * 128;
#pragma unroll
        for (int n = 0; n < 4; n++) {
          float e0 = __builtin_amdgcn_exp2f(sf[n][qi][0]);
          float e1 = __builtin_amdgcn_exp2f(sf[n][qi][1]);
          float e2 = __builtin_amdgcn_exp2f(sf[n][qi][2]);
          float e3 = __builtin_amdgcn_exp2f(sf[n][qi][3]);
          unsigned u01, u23;
          asm("v_cvt_pk_bf16_f32 %0, %1, %2" : "=v"(u01) : "v"(e0), "v"(e1));
          asm("v_cvt_pk_bf16_f32 %0, %1, %2" : "=v"(u23) : "v"(e2), "v"(e3));
          u32x2 w = {u01, u23};
          *(u32x2*)(pwr + ((n * 32 + fq * 8) ^ pswz)) = w;
        }
        asm volatile("" ::: "memory");
#pragma unroll
        for (int kk = 0; kk < 2; kk++) {
          int cb = kk * 64 + (fq << 4);
          s16x8 pa = ldsfrag(pw, fr, cb);
          psum[qi] = mfma16(pa, ones, psum[qi]);
#pragma unroll
          for (int n = 0; n < 4; n++) {
            s16x8 vf = ldsfrag(Vc, n * 16 + fr, cb);
            o[n][qi] = mfma16(pa, vf, o[n][qi]);
          }
        }
        asm volatile("" ::: "memory");
      }
    }
    __syncthreads();
  }

  // normalize + store via per-wave LDS staging, one 16-row group at a time
#pragma unroll
  for (int qi = 0; qi < 2; qi++) {
    float inv[4];
#pragma unroll
    for (int i = 0; i < 4; i++) inv[i] = 1.0f / psum[qi][i];
#pragma unroll
    for (int n = 0; n < 4; n++) {
      float e0 = o[n][qi][0] * inv[0], e1 = o[n][qi][1] * inv[1];
      float e2 = o[n][qi][2] * inv[2], e3 = o[n][qi][3] * inv[3];
      unsigned u01, u23;
      asm("v_cvt_pk_bf16_f32 %0, %1, %2" : "=v"(u01) : "v"(e0), "v"(e1));
      asm("v_cvt_pk_bf16_f32 %0, %1, %2" : "=v"(u23) : "v"(e2), "v"(e3));
      int colb = n * 32 + fr * 2;
#pragma unroll
      for (int i = 0; i < 4; i++) {
        int r = fq * 4 + i;
        unsigned v16 = (i == 0) ? (u01 & 0xffffu) : (i == 1) ? (u01 >> 16)
                      : (i == 2) ? (u23 & 0xffffu) : (u23 >> 16);
        *(short*)(pw + r * 128 + (colb ^ ((r & 7) << 4))) = (short)v16;
      }
    }
    asm volatile("" ::: "memory");
    int orow = lane >> 2;
    int cbase = (lane & 3) * 32;
    int swo = (orow & 7) << 4;
    s16x8 ov0 = *(const s16x8*)(pw + orow * 128 + (cbase ^ swo));
    s16x8 ov1 = *(const s16x8*)(pw + orow * 128 + ((cbase + 16) ^ swo));
    ushort* dst = O + (size_t)(b * SS + bx * 128 + wid * 32 + qi * 16 + orow) * DM + h * 64 + (lane & 3) * 16;
    *(s16x8*)(dst)     = ov0;
    *(s16x8*)(dst + 8) = ov1;
    asm volatile("" ::: "memory");
  }
}

// ---------------- launcher ----------------
extern "C" void kernel_launch(void* const* d_in, const int* in_sizes, int n_in,
                              void* d_out, int out_size, void* d_ws, size_t ws_size,
                              hipStream_t stream) {
  const float* x  = (const float*)d_in[0];
  const float* Wq = (const float*)d_in[1];
  const float* Wk = (const float*)d_in[2];
  const float* Wv = (const float*)d_in[3];
  const float* Wo = (const float*)d_in[4];
  char* ws = (char*)d_ws;
  ushort* xb    = (ushort*)(ws);                         // 16 MB : x bf16 [4096][2048]
  ushort* Wqkvt = (ushort*)(ws + 16777216);              // 12 MB : [3072][2048]
  ushort* Wot   = (ushort*)(ws + 29360128);              //  8 MB : [2048][2048]
  ushort* QKV   = (ushort*)(ws + 37748736);              // 24 MB : [4096][3072]
  ushort* Vt    = (ushort*)(ws + 62914560);              //  4 MB : [1024][2048]
  ushort* Obuf  = (ushort*)(ws + 67108864);              // 16 MB : [4096][2048]
  // RoPE table (512 KB): ws tail if it fits, else d_out (overwritten later by gemm2)
  float* rtab = (ws_size >= (size_t)83886080 + 524288)
              ? (float*)(ws + 83886080) : (float*)d_out;

  k_wpre<<<18688, 256, 0, stream>>>(x, Wq, Wk, Wv, Wo, xb, Wqkvt, Wot, rtab);
  k_gemm<1, 1><<<dim3(24, 32), 256, 0, stream>>>(xb, Wqkvt, (void*)QKV, rtab, Vt, MT, NQKVC, DM);
  k_attn<<<dim3(16, 64), 256, 0, stream>>>(QKV, Vt, Obuf);
  k_gemm<0, 0><<<dim3(16, 32), 256, 0, stream>>>(Obuf, Wot, d_out, nullptr, nullptr, MT, DM, DM);
}